// Round 7
// baseline (474.529 us; speedup 1.0000x reference)
//
#include <hip/hip_runtime.h>
#include <cmath>

#define HIDC 48

// ---------------------------------------------------------------------------
// block-wide mean/var over NPIX values spread across 16 waves (1024 threads).
// ---------------------------------------------------------------------------
__device__ __forceinline__ void block_meanvar1024(float s, float s2, float* red,
                                                  float cntinv, float& m, float& v)
{
#pragma unroll
    for (int off = 32; off > 0; off >>= 1) {
        s  += __shfl_down(s, off);
        s2 += __shfl_down(s2, off);
    }
    int wid  = threadIdx.x >> 6;   // 0..15
    int lane = threadIdx.x & 63;
    if (lane == 0) { red[wid] = s; red[16 + wid] = s2; }
    __syncthreads();
    if (threadIdx.x == 0) {
        float ts = 0.f, ts2 = 0.f;
#pragma unroll
        for (int i = 0; i < 16; ++i) { ts += red[i]; ts2 += red[16 + i]; }
        red[32] = ts; red[33] = ts2;
    }
    __syncthreads();
    float mean = red[32] * cntinv;
    m = mean;
    v = red[33] * cntinv - mean * mean;
    __syncthreads();
}

// ---------------------------------------------------------------------------
// Split-K partial conv3x3(SAME, zero-pad), NO bias (bias cancels in the
// following instance-norm; SK-conv bias is added in apply_fused).
// Each block: COG couts x ROWS rows x W cols over NCH=24 input channels
// (half = blockIdx.z&1, n = blockIdx.z>>1); partial written to
// out + half*4*COUT*NPIX; the following norm sums the partials.
//
// r7 staging rework: tiles span the FULL image width, so the x=-1 / x=W
// halo columns are ALWAYS zero and each channel's staged rows are
// contiguous 16B-aligned runs. LDS layout: interior at col 0, PW=W+4
// (pad cols W..W+3 pre-zeroed; +4 guard words in front of each buffer for
// the x=-1 read of row 0). Staging = float4 global loads + ds_write_b128
// (uniform banks, conflict-free); window reads = 3x ds_read_b64 per row
// hitting guard/pad zeros at the edges. Per-slot offsets precomputed once.
// CPS=4 at 64x64 too (halves barriers; 13.1KB LDS x 8 blocks/CU fits).
//  - r3 lesson: never stage strided-by-4 global reads (cacheline blowup).
//  - r5 lesson: no grid-wide syncs (54us each); separate dispatches.
// ---------------------------------------------------------------------------
template <int H, int W, int ROWS, int COG, int CPS, int PXT, int NCH>
__global__ __launch_bounds__(ROWS*(W/PXT)) void conv_tile(
    const float* __restrict__ in,    // (N, 48, H, W)
    const float* __restrict__ wgt,   // (COUT, 48, 3, 3)
    float* __restrict__ out)         // (2, N, COUT, H, W) partials
{
    constexpr int THREADS = ROWS * (W / PXT);
    constexpr int NPIX  = H * W;
    constexpr int PW    = W + 4;
    constexpr int TROWS = ROWS + 2;
    constexpr int CHSZ  = TROWS * PW;
    constexpr int LSZ   = CPS * CHSZ;
    constexpr int TXN   = W / PXT;          // threads per row
    constexpr int NS    = NCH / CPS;
    constexpr int F4R   = W / 4;            // float4 slots per row
    constexpr int NSLOT = CPS * TROWS * F4R;
    constexpr int LPT4  = (NSLOT + THREADS - 1) / THREADS;

    __shared__ float plane[2][LSZ + 4];     // +4 guard words lead each buffer

    const int t    = threadIdx.x;
    const int cg   = blockIdx.x;
    const int rt   = blockIdx.y;
    const int z    = blockIdx.z;
    const int half = z & 1;
    const int n    = z >> 1;
    const int COUT = gridDim.x * COG;
    const int co0  = cg * COG;
    const int cin0 = half * NCH;
    const int tx   = t % TXN;
    const int ty   = t / TXN;               // row within tile
    const int x0   = tx * PXT;
    const int r0   = rt * ROWS;
    const size_t OSTRIDE = (size_t)4 * COUT * NPIX;

    // zero both buffers entirely once (guards + pad cols; interior is
    // overwritten each stage). Barrier: init must precede stage-0 writes.
    for (int i = t; i < 2 * (LSZ + 4); i += THREADS)
        ((float*)plane)[i] = 0.f;
    __syncthreads();

    float acc[COG][PXT];
#pragma unroll
    for (int co = 0; co < COG; ++co)
#pragma unroll
        for (int p = 0; p < PXT; ++p) acc[co][p] = 0.f;

    const float* inb = in + ((size_t)n * 48 + cin0) * NPIX;

    // per-slot offsets (stage-invariant). goff=-1 => OOB row (write zeros);
    // loff=-1 => no slot for this (t,k).
    int goff[LPT4], loff[LPT4];
#pragma unroll
    for (int k = 0; k < LPT4; ++k) {
        int i = t + k * THREADS;
        loff[k] = -1; goff[k] = -1;
        if (i < NSLOT) {
            int ch  = i / (TROWS * F4R);
            int rem = i % (TROWS * F4R);
            int row = rem / F4R, j4 = rem % F4R;
            int gy  = r0 + row - 1;
            loff[k] = ch * CHSZ + row * PW + 4 * j4;
            if (gy >= 0 && gy < H)
                goff[k] = ch * NPIX + gy * W + 4 * j4;
        }
    }

    const float4 z4 = make_float4(0.f, 0.f, 0.f, 0.f);
    float4 pref[LPT4];
#pragma unroll
    for (int k = 0; k < LPT4; ++k)
        pref[k] = (goff[k] >= 0) ? *(const float4*)(inb + goff[k]) : z4;

    int buf = 0;
    for (int s = 0; s < NS; ++s) {
        float4 cur[LPT4];
#pragma unroll
        for (int k = 0; k < LPT4; ++k) cur[k] = pref[k];
        if (s + 1 < NS) {
            const float* nb = inb + (size_t)(s + 1) * CPS * NPIX;
#pragma unroll
            for (int k = 0; k < LPT4; ++k)
                pref[k] = (goff[k] >= 0) ? *(const float4*)(nb + goff[k]) : z4;
        }
#pragma unroll
        for (int k = 0; k < LPT4; ++k)
            if (loff[k] >= 0)
                *(float4*)&plane[buf][4 + loff[k]] = cur[k];
        __syncthreads();

#pragma unroll
        for (int c = 0; c < CPS; ++c) {
            const float* P = &plane[buf][4 + c * CHSZ];
            float wv[COG][9];
#pragma unroll
            for (int co = 0; co < COG; ++co)
#pragma unroll
                for (int k = 0; k < 9; ++k)
                    wv[co][k] = wgt[((size_t)(co0 + co) * 48 + cin0 + s * CPS + c) * 9 + k];
            // window rows ty..ty+2, cols x0-1 .. x0+PXT  (interior at col 0;
            // col -1 hits guard/pad zeros, col W..W+1 hit pad zeros)
            float vr[3][PXT + 2];
            if constexpr (PXT == 2) {
#pragma unroll
                for (int r = 0; r < 3; ++r) {
                    const float* rp = P + (ty + r) * PW + x0;
                    float2 a = *(const float2*)(rp - 2);
                    float2 b = *(const float2*)(rp);
                    float2 c2 = *(const float2*)(rp + 2);
                    vr[r][0] = a.y; vr[r][1] = b.x; vr[r][2] = b.y; vr[r][3] = c2.x;
                }
            } else {
#pragma unroll
                for (int r = 0; r < 3; ++r)
#pragma unroll
                    for (int j = 0; j < PXT + 2; ++j)
                        vr[r][j] = P[(ty + r) * PW + x0 - 1 + j];
            }
#pragma unroll
            for (int co = 0; co < COG; ++co)
#pragma unroll
                for (int p = 0; p < PXT; ++p) {
                    float s0 = vr[0][p]     * wv[co][0] + vr[0][p + 1] * wv[co][1]
                             + vr[0][p + 2] * wv[co][2] + vr[1][p]     * wv[co][3]
                             + vr[1][p + 1] * wv[co][4] + vr[1][p + 2] * wv[co][5]
                             + vr[2][p]     * wv[co][6] + vr[2][p + 1] * wv[co][7]
                             + vr[2][p + 2] * wv[co][8];
                    acc[co][p] += s0;
                }
        }
        buf ^= 1;
    }

#pragma unroll
    for (int co = 0; co < COG; ++co) {
        float* op = out + half * OSTRIDE
                  + (((size_t)n * COUT + co0 + co) * H + r0 + ty) * W + x0;
        if (PXT == 2) {
            *(float2*)op = make_float2(acc[co][0], acc[co][1]);
        } else {
#pragma unroll
            for (int p = 0; p < PXT; ++p) op[p] = acc[co][p];
        }
    }
}

// ---------------------------------------------------------------------------
// Per-plane epilogue on the SUM of two split-K partials:
//   MODE 0: inorm, prelu, inorm, +res    MODE 1: inorm, prelu
//   POOL 1: (MODE 0 only, NPIX=4096) thread owns a 2x2 quad; after the
//           residual add, pools max-2x2 in-register and writes the 32x32
//           plane (fuses maxpool2, saves a dispatch + round-trip).
// ---------------------------------------------------------------------------
template <int NPIX, int MODE, int POOL>
__global__ __launch_bounds__(1024) void norm_block(
    const float* __restrict__ c0,
    const float* __restrict__ c1,
    const float* __restrict__ res,
    const float* __restrict__ aptr,
    float* __restrict__ out)
{
    constexpr int TY = NPIX / 1024;
    __shared__ float red[34];
    const int t  = threadIdx.x;
    const int co = blockIdx.x;
    const int n  = blockIdx.y;
    const size_t base = ((size_t)n * 48 + co) * NPIX;
    constexpr float cntinv = 1.f / (float)NPIX;

    float acc[TY];
    size_t q = 0;
    if constexpr (POOL) {
        const int i = t >> 5, j = t & 31;       // quad (2i,2j)
        q = base + (size_t)i * 128 + j * 2;
        float2 a0 = *(const float2*)(c0 + q);
        float2 a1 = *(const float2*)(c0 + q + 64);
        float2 b0 = *(const float2*)(c1 + q);
        float2 b1 = *(const float2*)(c1 + q + 64);
        acc[0] = a0.x + b0.x; acc[1] = a0.y + b0.y;
        acc[2] = a1.x + b1.x; acc[3] = a1.y + b1.y;
    } else {
#pragma unroll
        for (int r = 0; r < TY; ++r)
            acc[r] = c0[base + t + r * 1024] + c1[base + t + r * 1024];
    }

    {
        float s = 0.f, s2 = 0.f;
#pragma unroll
        for (int r = 0; r < TY; ++r) { s += acc[r]; s2 += acc[r] * acc[r]; }
        float m, v;
        block_meanvar1024(s, s2, red, cntinv, m, v);
        float rr = rsqrtf(v + 1e-5f);
#pragma unroll
        for (int r = 0; r < TY; ++r) acc[r] = (acc[r] - m) * rr;
    }

    const float a = aptr[0];
#pragma unroll
    for (int r = 0; r < TY; ++r) acc[r] = acc[r] >= 0.f ? acc[r] : a * acc[r];

    if (MODE == 0) {
        float s = 0.f, s2 = 0.f;
#pragma unroll
        for (int r = 0; r < TY; ++r) { s += acc[r]; s2 += acc[r] * acc[r]; }
        float m, v;
        block_meanvar1024(s, s2, red, cntinv, m, v);
        float rr = rsqrtf(v + 1e-5f);
        if constexpr (POOL) {
            float2 r0v = *(const float2*)(res + q);
            float2 r1v = *(const float2*)(res + q + 64);
            acc[0] = (acc[0] - m) * rr + r0v.x;
            acc[1] = (acc[1] - m) * rr + r0v.y;
            acc[2] = (acc[2] - m) * rr + r1v.x;
            acc[3] = (acc[3] - m) * rr + r1v.y;
        } else {
#pragma unroll
            for (int r = 0; r < TY; ++r)
                acc[r] = (acc[r] - m) * rr + res[base + t + r * 1024];
        }
    }

    if constexpr (POOL) {
        out[(((size_t)n * 48 + co) << 10) + t] =
            fmaxf(fmaxf(acc[0], acc[1]), fmaxf(acc[2], acc[3]));
    } else {
#pragma unroll
        for (int r = 0; r < TY; ++r) out[base + t + r * 1024] = acc[r];
    }
}

// ---------------------------------------------------------------------------
__global__ __launch_bounds__(256) void downsample4(const float* __restrict__ xin,
                                                   float* __restrict__ o)
{
    int idx = blockIdx.x * 256 + threadIdx.x;        // 786432
    int j = idx & 63;
    int i = (idx >> 6) & 63;
    int nc = idx >> 12;
    o[idx] = xin[((size_t)nc * 256 + i * 4) * 256 + j * 4];
}

// ---------------------------------------------------------------------------
// Fused: bilinear 8x upsample of skernel partials (sk0+sk1+bias), per-pixel
// softmax, 3x3 reflect-padded apply to x. Grid (16, 256). Halo via
// cross-lane shuffle; kvs p-major conflict-free; loads hoisted.
// ---------------------------------------------------------------------------
__global__ __launch_bounds__(256) void apply_fused(const float* __restrict__ x,
                                                   const float* __restrict__ sk0,
                                                   const float* __restrict__ sk1,
                                                   const float* __restrict__ kb2,
                                                   float* __restrict__ out)
{
    __shared__ float skr[9][2][32];
    __shared__ float kvs[9][256];    // p-major
    const int bx = blockIdx.x;
    const int n  = bx >> 2;
    const int cg = bx & 3;
    const int h  = blockIdx.y;
    const int t  = threadIdx.x;

    float fs = (float)h * 31.0f / 255.0f;
    int r0 = (int)fs;
    float fh = fs - (float)r0;
    int r1 = min(r0 + 1, 31);

    for (int i = t; i < 576; i += 256) {
        int p = i >> 6, rsel = (i >> 5) & 1, c = i & 31;
        int rr = rsel ? r1 : r0;
        int idx = ((n * 9 + p) * 32 + rr) * 32 + c;
        skr[p][rsel][c] = sk0[idx] + sk1[idx] + kb2[p];
    }
    __syncthreads();

    {
        float fcs = (float)t * 31.0f / 255.0f;
        int c0 = (int)fcs;
        float fx = fcs - (float)c0;
        int c1 = min(c0 + 1, 31);
        float kv[9];
        float mx = -1e30f;
#pragma unroll
        for (int p = 0; p < 9; ++p) {
            float v0 = skr[p][0][c0] * (1.f - fx) + skr[p][0][c1] * fx;
            float v1 = skr[p][1][c0] * (1.f - fx) + skr[p][1][c1] * fx;
            float v  = v0 * (1.f - fh) + v1 * fh;
            kv[p] = v;
            mx = fmaxf(mx, v);
        }
        float ss = 0.f;
#pragma unroll
        for (int p = 0; p < 9; ++p) { kv[p] = __expf(kv[p] - mx); ss += kv[p]; }
        float inv = 1.f / ss;
#pragma unroll
        for (int p = 0; p < 9; ++p) kvs[p][t] = kv[p] * inv;
    }
    __syncthreads();

    const int wq = t & 63;           // lane within wave == pixel quad
    const int cl = t >> 6;           // wave id == channel subgroup
    const int w4 = wq * 4;

    float kv[4][9];
#pragma unroll
    for (int p = 0; p < 9; ++p) {
        float4 v = *(const float4*)&kvs[p][w4];
        kv[0][p] = v.x; kv[1][p] = v.y; kv[2][p] = v.z; kv[3][p] = v.w;
    }

    const int hm  = (h == 0) ? 1 : h - 1;
    const int hp  = (h == 255) ? 254 : h + 1;

    const int c0ch = cg * 12 + cl * 3;
    const float* xb = x + ((size_t)n * HIDC + c0ch) * 65536;
    float* ob = out + ((size_t)n * HIDC + c0ch) * 65536;

    float4 F[3][3];
#pragma unroll
    for (int c = 0; c < 3; ++c) {
        const float* xp = xb + (size_t)c * 65536;
        F[c][0] = *(const float4*)(xp + hm * 256 + w4);
        F[c][1] = *(const float4*)(xp + h  * 256 + w4);
        F[c][2] = *(const float4*)(xp + hp * 256 + w4);
    }

#pragma unroll
    for (int c = 0; c < 3; ++c) {
        float4 fm = F[c][0];
        float4 fc = F[c][1];
        float4 fp = F[c][2];
        float lm = __shfl_up(fm.w, 1);   if (wq == 0)  lm = fm.y;
        float lc = __shfl_up(fc.w, 1);   if (wq == 0)  lc = fc.y;
        float lp = __shfl_up(fp.w, 1);   if (wq == 0)  lp = fp.y;
        float rmr = __shfl_down(fm.x, 1); if (wq == 63) rmr = fm.z;
        float rcr = __shfl_down(fc.x, 1); if (wq == 63) rcr = fc.z;
        float rpr = __shfl_down(fp.x, 1); if (wq == 63) rpr = fp.z;
        float vm[6] = { lm, fm.x, fm.y, fm.z, fm.w, rmr };
        float vc[6] = { lc, fc.x, fc.y, fc.z, fc.w, rcr };
        float vp[6] = { lp, fp.x, fp.y, fp.z, fp.w, rpr };
        float4 o;
        float* op = &o.x;
#pragma unroll
        for (int j = 0; j < 4; ++j) {
            op[j] = kv[j][0] * vm[j] + kv[j][1] * vm[j + 1] + kv[j][2] * vm[j + 2]
                  + kv[j][3] * vc[j] + kv[j][4] * vc[j + 1] + kv[j][5] * vc[j + 2]
                  + kv[j][6] * vp[j] + kv[j][7] * vp[j + 1] + kv[j][8] * vp[j + 2];
        }
        *(float4*)(ob + (size_t)c * 65536 + h * 256 + w4) = o;
    }
}

extern "C" void kernel_launch(void* const* d_in, const int* in_sizes, int n_in,
                              void* d_out, int out_size, void* d_ws, size_t ws_size,
                              hipStream_t stream)
{
    (void)in_sizes; (void)n_in; (void)out_size; (void)ws_size;
    const float* x       = (const float*)d_in[0];
    const float* x_      = (const float*)d_in[1];
    const float* pre1_w  = (const float*)d_in[2];
    const float* pre1_a  = (const float*)d_in[4];
    const float* pre2_w  = (const float*)d_in[5];
    const float* pre2_a  = (const float*)d_in[7];
    const float* prek_w1 = (const float*)d_in[8];
    const float* prek_a  = (const float*)d_in[10];
    const float* prek_w2 = (const float*)d_in[11];
    const float* prek_b2 = (const float*)d_in[12];
    float* out = (float*)d_out;

    float* A   = (float*)d_ws;          // (4,48,64,64) = 786432
    float* B   = A + 786432;            // (4,48,64,64)
    float* R0  = B + 786432;            // partial conv half0 (<= 786432)
    float* R1  = R0 + 786432;           // partial conv half1
    float* C   = R1 + 786432;           // (4,48,32,32) = 196608
    float* D   = C + 196608;            // (4,48,32,32)
    float* SK0 = D + 196608;            // (4,9,32,32) = 36864
    float* SK1 = SK0 + 36864;

    const int W1 = 48 * 48 * 9;

    downsample4<<<3072, 256, 0, stream>>>(x_, A);

    // ---- 3 basic blocks @64x64: split-K conv (2048 blocks x 128thd) ----
    conv_tile<64, 64, 4, 3, 4, 2, 24><<<dim3(16, 16, 8), 128, 0, stream>>>(A, pre1_w, R0);
    norm_block<4096, 0, 0><<<dim3(48, 4), 1024, 0, stream>>>(R0, R1, A, pre1_a, B);
    conv_tile<64, 64, 4, 3, 4, 2, 24><<<dim3(16, 16, 8), 128, 0, stream>>>(B, pre1_w + W1, R0);
    norm_block<4096, 0, 0><<<dim3(48, 4), 1024, 0, stream>>>(R0, R1, B, pre1_a + 1, A);
    conv_tile<64, 64, 4, 3, 4, 2, 24><<<dim3(16, 16, 8), 128, 0, stream>>>(A, pre1_w + 2 * W1, R0);
    // third norm fuses maxpool2 -> writes pooled 32x32 planes into C
    norm_block<4096, 0, 1><<<dim3(48, 4), 1024, 0, stream>>>(R0, R1, A, pre1_a + 2, C);

    // ---- 3 basic blocks @32x32: split-K conv (1536 blocks x 128thd) ----
    conv_tile<32, 32, 4, 2, 4, 1, 24><<<dim3(24, 8, 8), 128, 0, stream>>>(C, pre2_w, R0);
    norm_block<1024, 0, 0><<<dim3(48, 4), 1024, 0, stream>>>(R0, R0 + 196608, C, pre2_a, D);
    conv_tile<32, 32, 4, 2, 4, 1, 24><<<dim3(24, 8, 8), 128, 0, stream>>>(D, pre2_w + W1, R0);
    norm_block<1024, 0, 0><<<dim3(48, 4), 1024, 0, stream>>>(R0, R0 + 196608, D, pre2_a + 1, C);
    conv_tile<32, 32, 4, 2, 4, 1, 24><<<dim3(24, 8, 8), 128, 0, stream>>>(C, pre2_w + 2 * W1, R0);
    norm_block<1024, 0, 0><<<dim3(48, 4), 1024, 0, stream>>>(R0, R0 + 196608, C, pre2_a + 2, D);

    // ---- kernel-prediction heads ----
    conv_tile<32, 32, 4, 2, 4, 1, 24><<<dim3(24, 8, 8), 128, 0, stream>>>(D, prek_w1, R0);
    norm_block<1024, 1, 0><<<dim3(48, 4), 1024, 0, stream>>>(R0, R0 + 196608, nullptr, prek_a, C);
    conv_tile<32, 32, 4, 3, 4, 1, 24><<<dim3(3, 8, 8), 128, 0, stream>>>(C, prek_w2, SK0);

    apply_fused<<<dim3(16, 256), 256, 0, stream>>>(x, SK0, SK1, prek_b2, out);
}

// Round 8
// 303.175 us; speedup vs baseline: 1.5652x; 1.5652x over previous
//
#include <hip/hip_runtime.h>
#include <cmath>

#define HIDC 48

// ---------------------------------------------------------------------------
// block-wide mean/var over NPIX values spread across 16 waves (1024 threads).
// ---------------------------------------------------------------------------
__device__ __forceinline__ void block_meanvar1024(float s, float s2, float* red,
                                                  float cntinv, float& m, float& v)
{
#pragma unroll
    for (int off = 32; off > 0; off >>= 1) {
        s  += __shfl_down(s, off);
        s2 += __shfl_down(s2, off);
    }
    int wid  = threadIdx.x >> 6;   // 0..15
    int lane = threadIdx.x & 63;
    if (lane == 0) { red[wid] = s; red[16 + wid] = s2; }
    __syncthreads();
    if (threadIdx.x == 0) {
        float ts = 0.f, ts2 = 0.f;
#pragma unroll
        for (int i = 0; i < 16; ++i) { ts += red[i]; ts2 += red[16 + i]; }
        red[32] = ts; red[33] = ts2;
    }
    __syncthreads();
    float mean = red[32] * cntinv;
    m = mean;
    v = red[33] * cntinv - mean * mean;
    __syncthreads();
}

// ---------------------------------------------------------------------------
// Split-K partial conv3x3(SAME, zero-pad), NO bias (bias cancels in the
// following instance-norm; SK-conv bias is added in apply_fused).
// Each block: COG couts x ROWS rows x W cols over NCH=24 input channels
// (half = blockIdx.z&1, n = blockIdx.z>>1); partial written to
// out + half*4*COUT*NPIX; the following norm sums the partials.
// Grid @64²: 2048 blocks x 128thd (8 blocks/CU, 16 waves/CU) — conv is
// latency-bound, occupancy is the first-order term (r6 win).
//  - SCALAR staging (r7 lesson: float4 staging tuples got demoted to
//    scratch -> 143MB of write-back per dispatch, 57us. Keep scalars.)
//  - Stage addresses precomputed ONCE into off[] (-1 = zero pad).
//  - PW = W+4: conflict-free float2/scalar LDS windows (2 lanes/bank max).
//  - Double-buffered LDS, ONE barrier per stage (stage s+1 writes the
//    buffer read at s-1 => safe).
//  - r3 lesson: never stage strided-by-4 global reads (cacheline blowup).
//  - r5 lesson: no grid-wide syncs (54us each); separate dispatches.
// ---------------------------------------------------------------------------
template <int H, int W, int ROWS, int COG, int CPS, int PXT, int NCH>
__global__ __launch_bounds__(ROWS*(W/PXT)) void conv_tile(
    const float* __restrict__ in,    // (N, 48, H, W)
    const float* __restrict__ wgt,   // (COUT, 48, 3, 3)
    float* __restrict__ out)         // (2, N, COUT, H, W) partials
{
    constexpr int THREADS = ROWS * (W / PXT);
    constexpr int NPIX = H * W;
    constexpr int PW   = W + 4;
    constexpr int CHSZ = (ROWS + 2) * PW;
    constexpr int LSZ  = CPS * CHSZ;
    constexpr int TXN  = W / PXT;          // threads per row
    constexpr int NS   = NCH / CPS;
    constexpr int LPT  = (LSZ + THREADS - 1) / THREADS;

    __shared__ float plane[2][LSZ];

    const int t    = threadIdx.x;
    const int cg   = blockIdx.x;
    const int rt   = blockIdx.y;
    const int z    = blockIdx.z;
    const int half = z & 1;
    const int n    = z >> 1;
    const int COUT = gridDim.x * COG;
    const int co0  = cg * COG;
    const int cin0 = half * NCH;
    const int tx   = t % TXN;
    const int ty   = t / TXN;              // row within tile
    const int x0   = tx * PXT;
    const int r0   = rt * ROWS;
    const size_t OSTRIDE = (size_t)4 * COUT * NPIX;

    float acc[COG][PXT];
#pragma unroll
    for (int co = 0; co < COG; ++co)
#pragma unroll
        for (int p = 0; p < PXT; ++p) acc[co][p] = 0.f;

    const float* inb = in + ((size_t)n * 48 + cin0) * NPIX;

    // precompute staging offsets (loop-invariant across stages)
    int off[LPT];
#pragma unroll
    for (int k = 0; k < LPT; ++k) {
        int i = t + k * THREADS;
        off[k] = -1;
        if (i < LSZ) {
            int ch  = i / CHSZ;
            int rem = i % CHSZ;
            int ly  = rem / PW, lx = rem % PW;
            int gy  = r0 + ly - 1, gx = lx - 1;
            if (gy >= 0 && gy < H && gx >= 0 && gx < W)
                off[k] = ch * NPIX + gy * W + gx;
        }
    }

    // prefetch stage 0
    float pref[LPT];
#pragma unroll
    for (int k = 0; k < LPT; ++k)
        pref[k] = (off[k] >= 0) ? inb[off[k]] : 0.f;

    int buf = 0;
    for (int s = 0; s < NS; ++s) {
        float cur[LPT];
#pragma unroll
        for (int k = 0; k < LPT; ++k) cur[k] = pref[k];
        if (s + 1 < NS) {
            const float* nb = inb + (size_t)(s + 1) * CPS * NPIX;
#pragma unroll
            for (int k = 0; k < LPT; ++k)
                pref[k] = (off[k] >= 0) ? nb[off[k]] : 0.f;
        }
#pragma unroll
        for (int k = 0; k < LPT; ++k) {
            int i = t + k * THREADS;
            if (i < LSZ) plane[buf][i] = cur[k];
        }
        __syncthreads();

#pragma unroll
        for (int c = 0; c < CPS; ++c) {
            const float* P = &plane[buf][c * CHSZ];
            float wv[COG][9];
#pragma unroll
            for (int co = 0; co < COG; ++co)
#pragma unroll
                for (int k = 0; k < 9; ++k)
                    wv[co][k] = wgt[((size_t)(co0 + co) * 48 + cin0 + s * CPS + c) * 9 + k];
            // window rows ty..ty+2, cols x0..x0+PXT+1
            float vr[3][PXT + 2];
            if constexpr (PXT == 2) {
#pragma unroll
                for (int r = 0; r < 3; ++r) {
                    float2 a = *(const float2*)(P + (ty + r) * PW + x0);
                    float2 b = *(const float2*)(P + (ty + r) * PW + x0 + 2);
                    vr[r][0] = a.x; vr[r][1] = a.y; vr[r][2] = b.x; vr[r][3] = b.y;
                }
            } else {
#pragma unroll
                for (int r = 0; r < 3; ++r)
#pragma unroll
                    for (int j = 0; j < PXT + 2; ++j)
                        vr[r][j] = P[(ty + r) * PW + x0 + j];
            }
#pragma unroll
            for (int co = 0; co < COG; ++co)
#pragma unroll
                for (int p = 0; p < PXT; ++p) {
                    float s0 = vr[0][p]     * wv[co][0] + vr[0][p + 1] * wv[co][1]
                             + vr[0][p + 2] * wv[co][2] + vr[1][p]     * wv[co][3]
                             + vr[1][p + 1] * wv[co][4] + vr[1][p + 2] * wv[co][5]
                             + vr[2][p]     * wv[co][6] + vr[2][p + 1] * wv[co][7]
                             + vr[2][p + 2] * wv[co][8];
                    acc[co][p] += s0;
                }
        }
        buf ^= 1;
    }

#pragma unroll
    for (int co = 0; co < COG; ++co) {
        float* op = out + half * OSTRIDE
                  + (((size_t)n * COUT + co0 + co) * H + r0 + ty) * W + x0;
        if (PXT == 2) {
            *(float2*)op = make_float2(acc[co][0], acc[co][1]);
        } else {
#pragma unroll
            for (int p = 0; p < PXT; ++p) op[p] = acc[co][p];
        }
    }
}

// ---------------------------------------------------------------------------
// Per-plane epilogue on the SUM of two split-K partials:
//   MODE 0: inorm, prelu, inorm, +res    MODE 1: inorm, prelu
//   POOL 1: (MODE 0 only, NPIX=4096) thread owns a 2x2 quad; after the
//           residual add, pools max-2x2 in-register and writes the 32x32
//           plane (fuses maxpool2, saves a dispatch + round-trip).
// r8: non-POOL TY=4 path vectorized — thread owns t*4..t*4+3 (stats are
// permutation-invariant; res/out positions stay consistent): 12 scalar
// loads + 4 stores -> 3x dwordx4 + 1x dwordx4.
// ---------------------------------------------------------------------------
template <int NPIX, int MODE, int POOL>
__global__ __launch_bounds__(1024) void norm_block(
    const float* __restrict__ c0,
    const float* __restrict__ c1,
    const float* __restrict__ res,
    const float* __restrict__ aptr,
    float* __restrict__ out)
{
    constexpr int TY = NPIX / 1024;
    constexpr bool VEC = (TY == 4) && (POOL == 0);
    __shared__ float red[34];
    const int t  = threadIdx.x;
    const int co = blockIdx.x;
    const int n  = blockIdx.y;
    const size_t base = ((size_t)n * 48 + co) * NPIX;
    constexpr float cntinv = 1.f / (float)NPIX;

    float acc[TY];
    size_t q = 0;
    if constexpr (POOL) {
        const int i = t >> 5, j = t & 31;       // quad (2i,2j)
        q = base + (size_t)i * 128 + j * 2;
        float2 a0 = *(const float2*)(c0 + q);
        float2 a1 = *(const float2*)(c0 + q + 64);
        float2 b0 = *(const float2*)(c1 + q);
        float2 b1 = *(const float2*)(c1 + q + 64);
        acc[0] = a0.x + b0.x; acc[1] = a0.y + b0.y;
        acc[2] = a1.x + b1.x; acc[3] = a1.y + b1.y;
    } else if constexpr (VEC) {
        q = base + (size_t)t * 4;
        float4 a4 = *(const float4*)(c0 + q);
        float4 b4 = *(const float4*)(c1 + q);
        acc[0] = a4.x + b4.x; acc[1] = a4.y + b4.y;
        acc[2] = a4.z + b4.z; acc[3] = a4.w + b4.w;
    } else {
#pragma unroll
        for (int r = 0; r < TY; ++r)
            acc[r] = c0[base + t + r * 1024] + c1[base + t + r * 1024];
    }

    {
        float s = 0.f, s2 = 0.f;
#pragma unroll
        for (int r = 0; r < TY; ++r) { s += acc[r]; s2 += acc[r] * acc[r]; }
        float m, v;
        block_meanvar1024(s, s2, red, cntinv, m, v);
        float rr = rsqrtf(v + 1e-5f);
#pragma unroll
        for (int r = 0; r < TY; ++r) acc[r] = (acc[r] - m) * rr;
    }

    const float a = aptr[0];
#pragma unroll
    for (int r = 0; r < TY; ++r) acc[r] = acc[r] >= 0.f ? acc[r] : a * acc[r];

    if (MODE == 0) {
        float s = 0.f, s2 = 0.f;
#pragma unroll
        for (int r = 0; r < TY; ++r) { s += acc[r]; s2 += acc[r] * acc[r]; }
        float m, v;
        block_meanvar1024(s, s2, red, cntinv, m, v);
        float rr = rsqrtf(v + 1e-5f);
        if constexpr (POOL) {
            float2 r0v = *(const float2*)(res + q);
            float2 r1v = *(const float2*)(res + q + 64);
            acc[0] = (acc[0] - m) * rr + r0v.x;
            acc[1] = (acc[1] - m) * rr + r0v.y;
            acc[2] = (acc[2] - m) * rr + r1v.x;
            acc[3] = (acc[3] - m) * rr + r1v.y;
        } else if constexpr (VEC) {
            float4 r4 = *(const float4*)(res + q);
            acc[0] = (acc[0] - m) * rr + r4.x;
            acc[1] = (acc[1] - m) * rr + r4.y;
            acc[2] = (acc[2] - m) * rr + r4.z;
            acc[3] = (acc[3] - m) * rr + r4.w;
        } else {
#pragma unroll
            for (int r = 0; r < TY; ++r)
                acc[r] = (acc[r] - m) * rr + res[base + t + r * 1024];
        }
    }

    if constexpr (POOL) {
        out[(((size_t)n * 48 + co) << 10) + t] =
            fmaxf(fmaxf(acc[0], acc[1]), fmaxf(acc[2], acc[3]));
    } else if constexpr (VEC) {
        *(float4*)(out + q) = make_float4(acc[0], acc[1], acc[2], acc[3]);
    } else {
#pragma unroll
        for (int r = 0; r < TY; ++r) out[base + t + r * 1024] = acc[r];
    }
}

// ---------------------------------------------------------------------------
__global__ __launch_bounds__(256) void downsample4(const float* __restrict__ xin,
                                                   float* __restrict__ o)
{
    int idx = blockIdx.x * 256 + threadIdx.x;        // 786432
    int j = idx & 63;
    int i = (idx >> 6) & 63;
    int nc = idx >> 12;
    o[idx] = xin[((size_t)nc * 256 + i * 4) * 256 + j * 4];
}

// ---------------------------------------------------------------------------
// Fused: bilinear 8x upsample of skernel partials (sk0+sk1+bias), per-pixel
// softmax, 3x3 reflect-padded apply to x. Grid (16, 256). Halo via
// cross-lane shuffle; kvs p-major conflict-free.
// r8: the 9 x-row float4 loads are issued at the TOP of the kernel — they
// are independent of skr staging / softmax / kvs, so their HBM latency
// hides under ~2us of softmax work + 2 barriers instead of being exposed.
// ---------------------------------------------------------------------------
__global__ __launch_bounds__(256) void apply_fused(const float* __restrict__ x,
                                                   const float* __restrict__ sk0,
                                                   const float* __restrict__ sk1,
                                                   const float* __restrict__ kb2,
                                                   float* __restrict__ out)
{
    __shared__ float skr[9][2][32];
    __shared__ float kvs[9][256];    // p-major
    const int bx = blockIdx.x;
    const int n  = bx >> 2;
    const int cg = bx & 3;
    const int h  = blockIdx.y;
    const int t  = threadIdx.x;

    const int wq = t & 63;           // lane within wave == pixel quad
    const int cl = t >> 6;           // wave id == channel subgroup
    const int w4 = wq * 4;
    const int hm  = (h == 0) ? 1 : h - 1;
    const int hp  = (h == 255) ? 254 : h + 1;
    const int c0ch = cg * 12 + cl * 3;
    const float* xb = x + ((size_t)n * HIDC + c0ch) * 65536;
    float* ob = out + ((size_t)n * HIDC + c0ch) * 65536;

    // issue all 9 x loads first (independent of everything below)
    float4 F[3][3];
#pragma unroll
    for (int c = 0; c < 3; ++c) {
        const float* xp = xb + (size_t)c * 65536;
        F[c][0] = *(const float4*)(xp + hm * 256 + w4);
        F[c][1] = *(const float4*)(xp + h  * 256 + w4);
        F[c][2] = *(const float4*)(xp + hp * 256 + w4);
    }

    float fs = (float)h * 31.0f / 255.0f;
    int r0 = (int)fs;
    float fh = fs - (float)r0;
    int r1 = min(r0 + 1, 31);

    for (int i = t; i < 576; i += 256) {
        int p = i >> 6, rsel = (i >> 5) & 1, c = i & 31;
        int rr = rsel ? r1 : r0;
        int idx = ((n * 9 + p) * 32 + rr) * 32 + c;
        skr[p][rsel][c] = sk0[idx] + sk1[idx] + kb2[p];
    }
    __syncthreads();

    {
        float fcs = (float)t * 31.0f / 255.0f;
        int c0 = (int)fcs;
        float fx = fcs - (float)c0;
        int c1 = min(c0 + 1, 31);
        float kv[9];
        float mx = -1e30f;
#pragma unroll
        for (int p = 0; p < 9; ++p) {
            float v0 = skr[p][0][c0] * (1.f - fx) + skr[p][0][c1] * fx;
            float v1 = skr[p][1][c0] * (1.f - fx) + skr[p][1][c1] * fx;
            float v  = v0 * (1.f - fh) + v1 * fh;
            kv[p] = v;
            mx = fmaxf(mx, v);
        }
        float ss = 0.f;
#pragma unroll
        for (int p = 0; p < 9; ++p) { kv[p] = __expf(kv[p] - mx); ss += kv[p]; }
        float inv = 1.f / ss;
#pragma unroll
        for (int p = 0; p < 9; ++p) kvs[p][t] = kv[p] * inv;
    }
    __syncthreads();

    float kv[4][9];
#pragma unroll
    for (int p = 0; p < 9; ++p) {
        float4 v = *(const float4*)&kvs[p][w4];
        kv[0][p] = v.x; kv[1][p] = v.y; kv[2][p] = v.z; kv[3][p] = v.w;
    }

#pragma unroll
    for (int c = 0; c < 3; ++c) {
        float4 fm = F[c][0];
        float4 fc = F[c][1];
        float4 fp = F[c][2];
        float lm = __shfl_up(fm.w, 1);   if (wq == 0)  lm = fm.y;
        float lc = __shfl_up(fc.w, 1);   if (wq == 0)  lc = fc.y;
        float lp = __shfl_up(fp.w, 1);   if (wq == 0)  lp = fp.y;
        float rmr = __shfl_down(fm.x, 1); if (wq == 63) rmr = fm.z;
        float rcr = __shfl_down(fc.x, 1); if (wq == 63) rcr = fc.z;
        float rpr = __shfl_down(fp.x, 1); if (wq == 63) rpr = fp.z;
        float vm[6] = { lm, fm.x, fm.y, fm.z, fm.w, rmr };
        float vc[6] = { lc, fc.x, fc.y, fc.z, fc.w, rcr };
        float vp[6] = { lp, fp.x, fp.y, fp.z, fp.w, rpr };
        float4 o;
        float* op = &o.x;
#pragma unroll
        for (int j = 0; j < 4; ++j) {
            op[j] = kv[j][0] * vm[j] + kv[j][1] * vm[j + 1] + kv[j][2] * vm[j + 2]
                  + kv[j][3] * vc[j] + kv[j][4] * vc[j + 1] + kv[j][5] * vc[j + 2]
                  + kv[j][6] * vp[j] + kv[j][7] * vp[j + 1] + kv[j][8] * vp[j + 2];
        }
        *(float4*)(ob + (size_t)c * 65536 + h * 256 + w4) = o;
    }
}

extern "C" void kernel_launch(void* const* d_in, const int* in_sizes, int n_in,
                              void* d_out, int out_size, void* d_ws, size_t ws_size,
                              hipStream_t stream)
{
    (void)in_sizes; (void)n_in; (void)out_size; (void)ws_size;
    const float* x       = (const float*)d_in[0];
    const float* x_      = (const float*)d_in[1];
    const float* pre1_w  = (const float*)d_in[2];
    const float* pre1_a  = (const float*)d_in[4];
    const float* pre2_w  = (const float*)d_in[5];
    const float* pre2_a  = (const float*)d_in[7];
    const float* prek_w1 = (const float*)d_in[8];
    const float* prek_a  = (const float*)d_in[10];
    const float* prek_w2 = (const float*)d_in[11];
    const float* prek_b2 = (const float*)d_in[12];
    float* out = (float*)d_out;

    float* A   = (float*)d_ws;          // (4,48,64,64) = 786432
    float* B   = A + 786432;            // (4,48,64,64)
    float* R0  = B + 786432;            // partial conv half0 (<= 786432)
    float* R1  = R0 + 786432;           // partial conv half1
    float* C   = R1 + 786432;           // (4,48,32,32) = 196608
    float* D   = C + 196608;            // (4,48,32,32)
    float* SK0 = D + 196608;            // (4,9,32,32) = 36864
    float* SK1 = SK0 + 36864;

    const int W1 = 48 * 48 * 9;

    downsample4<<<3072, 256, 0, stream>>>(x_, A);

    // ---- 3 basic blocks @64x64: split-K conv (2048 blocks x 128thd) ----
    conv_tile<64, 64, 4, 3, 2, 2, 24><<<dim3(16, 16, 8), 128, 0, stream>>>(A, pre1_w, R0);
    norm_block<4096, 0, 0><<<dim3(48, 4), 1024, 0, stream>>>(R0, R1, A, pre1_a, B);
    conv_tile<64, 64, 4, 3, 2, 2, 24><<<dim3(16, 16, 8), 128, 0, stream>>>(B, pre1_w + W1, R0);
    norm_block<4096, 0, 0><<<dim3(48, 4), 1024, 0, stream>>>(R0, R1, B, pre1_a + 1, A);
    conv_tile<64, 64, 4, 3, 2, 2, 24><<<dim3(16, 16, 8), 128, 0, stream>>>(A, pre1_w + 2 * W1, R0);
    // third norm fuses maxpool2 -> writes pooled 32x32 planes into C
    norm_block<4096, 0, 1><<<dim3(48, 4), 1024, 0, stream>>>(R0, R1, A, pre1_a + 2, C);

    // ---- 3 basic blocks @32x32: split-K conv (1536 blocks x 128thd) ----
    conv_tile<32, 32, 4, 2, 4, 1, 24><<<dim3(24, 8, 8), 128, 0, stream>>>(C, pre2_w, R0);
    norm_block<1024, 0, 0><<<dim3(48, 4), 1024, 0, stream>>>(R0, R0 + 196608, C, pre2_a, D);
    conv_tile<32, 32, 4, 2, 4, 1, 24><<<dim3(24, 8, 8), 128, 0, stream>>>(D, pre2_w + W1, R0);
    norm_block<1024, 0, 0><<<dim3(48, 4), 1024, 0, stream>>>(R0, R0 + 196608, D, pre2_a + 1, C);
    conv_tile<32, 32, 4, 2, 4, 1, 24><<<dim3(24, 8, 8), 128, 0, stream>>>(C, pre2_w + 2 * W1, R0);
    norm_block<1024, 0, 0><<<dim3(48, 4), 1024, 0, stream>>>(R0, R0 + 196608, C, pre2_a + 2, D);

    // ---- kernel-prediction heads ----
    conv_tile<32, 32, 4, 2, 4, 1, 24><<<dim3(24, 8, 8), 128, 0, stream>>>(D, prek_w1, R0);
    norm_block<1024, 1, 0><<<dim3(48, 4), 1024, 0, stream>>>(R0, R0 + 196608, nullptr, prek_a, C);
    conv_tile<32, 32, 4, 3, 4, 1, 24><<<dim3(3, 8, 8), 128, 0, stream>>>(C, prek_w2, SK0);

    apply_fused<<<dim3(16, 256), 256, 0, stream>>>(x, SK0, SK1, prek_b2, out);
}